// Round 10
// baseline (110.175 us; speedup 1.0000x reference)
//
#include <hip/hip_runtime.h>

// MLP: 64 × (Linear(5,5)+ReLU) then Linear(5,1), BATCH = 1048576 rows.
// R18: R17 + padded weight layout in d_ws -> 2× s_load_dwordx16 per layer.
//
// R17 post-mortem: touch-pipelining took but bought only 1.5 µs
// (46.1 µs @ 63.5% busy; VALU-busy pinned at ~29.3 µs = the minimal
// packed stream). Pre-committed read fired the SMEM-THROUGHPUT branch:
// per CU per layer, 16 waves × ~6 s_load requests (W[25]+b[5] merges as
// x8,x8,x8,dword,x4,dword) = ~96 scalar-cache requests for the same
// 120 B; the scalar pipe serializes them and all waves hit lgkmcnt
// together. Fix: prep kernel (same stream, graph-safe) packs weights
// into the R8 padded [64][32]-float layout in d_ws (128 B/layer,
// 64 B-aligned; W[25], b at 25..29, pad; W_out/b_out row at 2048).
// Main kernel loads each layer as two <16 x float> constant-AS loads ->
// exactly 2 s_load_dwordx16. Requests/CU/layer: 96 -> 32. ONE variable
// changed vs R17 (load width); ROWS=4, packed pk_fma, A/B buffers,
// TOUCH placement all identical.
//
// Pre-committed read: ~34-40 µs @ 75-85% busy => request-rate wall
// confirmed; ~46 µs @ ~63% => un-hidable latency -> try ROWS=8+x16,
// else declare roofline on this form.

#define MLP_DEPTH 64
#define MLP_D 5
#define ROWS 4
#define PAD_STRIDE 32               // floats per layer slot (128 B)
#define WS_N (MLP_DEPTH * PAD_STRIDE + 8)  // + output row

typedef float f2 __attribute__((ext_vector_type(2)));
typedef float f16v __attribute__((ext_vector_type(16)));
// Constant-address-space pointers: uniform loads select as s_load (SMEM).
typedef const float __attribute__((address_space(4)))* cfp;
typedef const f16v __attribute__((address_space(4)))* cf16p;

static __device__ __forceinline__ f2 splat2(float v) {
    f2 r; r.x = v; r.y = v; return r;
}

// Two s_load_dwordx16 per layer: lo = W[0..15], hi = W[16..24], b[0..4], pad.
struct WBs { f16v lo, hi; };

static __device__ __forceinline__ void loadWB(WBs& s, cfp wsb, int l) {
    const cf16p p = (const cf16p)(wsb + l * PAD_STRIDE);
    s.lo = p[0];
    s.hi = p[1];
}

// W[k] (k = j*5+i, compile-time) and bias b[j] from the two 16-wide regs.
#define WKk(S, k) ((k) < 16 ? (S).lo[(k)] : (S).hi[(k) - 16])
#define BIj(S, j) ((S).hi[9 + (j)])   // element 25+j

// Force the compiler's lgkmcnt(0) wait HERE (SMEM waits are
// all-or-nothing): reading one SGPR of S drains S's s_loads at this
// point, before the next prefetch issues. "memory" + sched_barrier keep
// later s_loads from hoisting above.
#define TOUCH(S)                                                  \
    do {                                                          \
        asm volatile("" ::"s"((S).hi[15]) : "memory");            \
        __builtin_amdgcn_sched_barrier(0);                        \
    } while (0)

// Packed row-fused layer: 2 row-pairs × 5 outputs = 10 independent
// pk_fma chains; each half-lane runs the exact fmaf chain of all prior
// rounds (absmax must stay 0.0). Weights are wave-uniform SGPRs
// (v_pk_fma_f32: one SGPR source, op_sel splat; bias costs 5 one-time
// v_movs per layer, amortized over the row-pairs).
static __device__ __forceinline__ void computeWB(const WBs& s, f2 h2[2][MLP_D]) {
#pragma unroll
    for (int p = 0; p < 2; ++p) {
        f2 acc[MLP_D];
#pragma unroll
        for (int j = 0; j < MLP_D; ++j)
            acc[j] = __builtin_elementwise_fma(
                h2[p][0], splat2(WKk(s, j * MLP_D + 0)), splat2(BIj(s, j)));
#pragma unroll
        for (int i = 1; i < MLP_D; ++i)
#pragma unroll
            for (int j = 0; j < MLP_D; ++j)
                acc[j] = __builtin_elementwise_fma(
                    h2[p][i], splat2(WKk(s, j * MLP_D + i)), acc[j]);
#pragma unroll
        for (int j = 0; j < MLP_D; ++j)
            h2[p][j] = __builtin_elementwise_max(acc[j], splat2(0.0f));
    }
}

// Prep: pack weights into padded layout (identical values, bit-exact).
__global__ void MLP_89687507075104_prep(
    const float* __restrict__ Ws, const float* __restrict__ bs,
    const float* __restrict__ W_out, const float* __restrict__ b_out,
    float* __restrict__ ws)
{
    const int idx = blockIdx.x * blockDim.x + threadIdx.x;
    if (idx >= WS_N) return;
    float v;
    if (idx < MLP_DEPTH * PAD_STRIDE) {
        const int l = idx >> 5, k = idx & 31;
        v = (k < 25) ? Ws[l * 25 + k]
          : (k < 30) ? bs[l * MLP_D + (k - 25)]
          : 0.0f;
    } else {
        const int k = idx - MLP_DEPTH * PAD_STRIDE;
        v = (k < MLP_D) ? W_out[k] : (k == MLP_D) ? b_out[0] : 0.0f;
    }
    ws[idx] = v;
}

__global__ __launch_bounds__(256, 4) void MLP_89687507075104_kernel(
    const float* __restrict__ x,      // [n, 5]
    const float* __restrict__ wsw,    // [64*32 + 8] packed weights
    float* __restrict__ out,          // [n]
    int n)
{
    const cfp wsb = (cfp)(unsigned long long)wsw;

    const int t = blockIdx.x * blockDim.x + threadIdx.x;
    const long row0 = (long)t * ROWS;
    if (row0 >= n) return;

    // rows row0..row0+3 = 20 contiguous floats (80 B, 16B-aligned).
    const float4* xp = reinterpret_cast<const float4*>(x + row0 * MLP_D);
    const float4 q0 = xp[0], q1 = xp[1], q2 = xp[2], q3 = xp[3], q4 = xp[4];
    // h2[p][i] = (h[2p][i], h[2p+1][i]) — row-paired into register pairs.
    f2 h2[2][MLP_D];
    h2[0][0].x=q0.x; h2[0][1].x=q0.y; h2[0][2].x=q0.z; h2[0][3].x=q0.w; h2[0][4].x=q1.x;
    h2[0][0].y=q1.y; h2[0][1].y=q1.z; h2[0][2].y=q1.w; h2[0][3].y=q2.x; h2[0][4].y=q2.y;
    h2[1][0].x=q2.z; h2[1][1].x=q2.w; h2[1][2].x=q3.x; h2[1][3].x=q3.y; h2[1][4].x=q3.z;
    h2[1][0].y=q3.w; h2[1][1].y=q4.x; h2[1][2].y=q4.y; h2[1][3].y=q4.z; h2[1][4].y=q4.w;

    WBs A, B;
    loadWB(A, wsb, 0);
    TOUCH(A);  // drain A(0) before loadB(1) issues: loop body stays clean

#pragma unroll 1
    for (int l = 0; l < MLP_DEPTH; l += 2) {
        loadWB(B, wsb, l + 1);          // issue; lands during computeA
        computeWB(A, h2);
        TOUCH(B);                       // wait B here (only B in flight)
        // Clamp keeps the final (redundant) prefetch in-bounds.
        const int ln = (l + 2 < MLP_DEPTH) ? (l + 2) : (MLP_DEPTH - 1);
        loadWB(A, wsb, ln);             // issue; lands during computeB
        computeWB(B, h2);
        TOUCH(A);                       // wait A here (only A in flight)
    }

    // Output layer: Linear(5,1) — packed (2 pk_fma chains), SGPR weights.
    const cfp ob = wsb + MLP_DEPTH * PAD_STRIDE;
    const float wo0 = ob[0], wo1 = ob[1], wo2 = ob[2], wo3 = ob[3];
    const float wo4 = ob[4], bo = ob[5];
    f2 o2[2];
#pragma unroll
    for (int p = 0; p < 2; ++p) {
        f2 acc = __builtin_elementwise_fma(h2[p][0], splat2(wo0), splat2(bo));
        acc = __builtin_elementwise_fma(h2[p][1], splat2(wo1), acc);
        acc = __builtin_elementwise_fma(h2[p][2], splat2(wo2), acc);
        acc = __builtin_elementwise_fma(h2[p][3], splat2(wo3), acc);
        acc = __builtin_elementwise_fma(h2[p][4], splat2(wo4), acc);
        o2[p] = acc;
    }
    float4 ov;
    ov.x = o2[0].x; ov.y = o2[0].y; ov.z = o2[1].x; ov.w = o2[1].y;
    *reinterpret_cast<float4*>(out + row0) = ov;
}

extern "C" void kernel_launch(void* const* d_in, const int* in_sizes, int n_in,
                              void* d_out, int out_size, void* d_ws, size_t ws_size,
                              hipStream_t stream) {
    const float* x     = (const float*)d_in[0];
    const float* Ws    = (const float*)d_in[1];
    const float* bs    = (const float*)d_in[2];
    const float* W_out = (const float*)d_in[3];
    const float* b_out = (const float*)d_in[4];
    float* out = (float*)d_out;
    float* ws  = (float*)d_ws;

    const int n = in_sizes[0] / MLP_D;  // batch rows (1048576)

    // Pack weights into padded SMEM-friendly layout (same stream ->
    // ordered before the main kernel; graph-capture safe).
    MLP_89687507075104_prep<<<(WS_N + 255) / 256, 256, 0, stream>>>(
        Ws, bs, W_out, b_out, ws);

    const int block = 256;
    const int threads_needed = (n + ROWS - 1) / ROWS;
    const int grid = (threads_needed + block - 1) / block;  // 1024
    MLP_89687507075104_kernel<<<grid, block, 0, stream>>>(x, ws, out, n);
}